// Round 1
// baseline (432.443 us; speedup 1.0000x reference)
//
#include <hip/hip_runtime.h>

#define UNITS 64

// Pass 1: out[i] = bias[i % 64]  (d_out is poisoned before every call)
__global__ void gc_init_bias(float* __restrict__ out, const float* __restrict__ bias, int total) {
    int i = blockIdx.x * blockDim.x + threadIdx.x;
    if (i < total) out[i] = bias[i & (UNITS - 1)];
}

// Pass 2: one wave per edge, one lane per output unit.
// out[rows[e]*64 + lane] += values[e] * kernel[cols[e]*64 + lane]
__global__ void gc_scatter(const int* __restrict__ rows, const int* __restrict__ cols,
                           const float* __restrict__ values, const float* __restrict__ kern,
                           float* __restrict__ out, int nnz) {
    int edge = blockIdx.x * (blockDim.x >> 6) + (threadIdx.x >> 6);
    int lane = threadIdx.x & 63;
    if (edge >= nnz) return;
    int r = rows[edge];
    int c = cols[edge];
    float v = values[edge];
    float k = kern[c * UNITS + lane];
    atomicAdd(&out[r * UNITS + lane], v * k);
}

// Pass 3: relu in place
__global__ void gc_relu(float* __restrict__ out, int total) {
    int i = blockIdx.x * blockDim.x + threadIdx.x;
    if (i < total) out[i] = fmaxf(out[i], 0.0f);
}

extern "C" void kernel_launch(void* const* d_in, const int* in_sizes, int n_in,
                              void* d_out, int out_size, void* d_ws, size_t ws_size,
                              hipStream_t stream) {
    const int*   rows   = (const int*)d_in[0];
    const int*   cols   = (const int*)d_in[1];
    const float* values = (const float*)d_in[2];
    const float* kern   = (const float*)d_in[3];
    const float* bias   = (const float*)d_in[4];
    float* out = (float*)d_out;

    int nnz   = in_sizes[0];
    int total = out_size;  // N * UNITS

    gc_init_bias<<<(total + 255) / 256, 256, 0, stream>>>(out, bias, total);

    const int edges_per_block = 256 / 64;  // 4 waves per block
    gc_scatter<<<(nnz + edges_per_block - 1) / edges_per_block, 256, 0, stream>>>(
        rows, cols, values, kern, out, nnz);

    gc_relu<<<(total + 255) / 256, 256, 0, stream>>>(out, total);
}